// Round 1
// baseline (1886.268 us; speedup 1.0000x reference)
//
#include <hip/hip_runtime.h>
#include <math.h>

#define BT 8192      // B*T
#define NDIM 512     // INPUT_DIM
#define NFREQ 257
#define NSPLIT 4
#define DDIM 128     // VQ_DIM
#define NEMBED 8192

// ---------------- K table: K_s[delta] = sum_{f: rm[f]==s} w_f cos(2*pi*f*delta/512) ----
__global__ __launch_bounds__(512) void build_K_kernel(const int* __restrict__ rm,
                                                      float* __restrict__ Kmat) {
    __shared__ float ctab[512];
    __shared__ int rms[NFREQ];
    int t = threadIdx.x;
    ctab[t] = cospif((float)t * (1.0f / 256.0f));   // cos(2*pi*t/512)
    if (t < NFREQ) rms[t] = rm[t];
    __syncthreads();
    float acc0 = 0.f, acc1 = 0.f, acc2 = 0.f, acc3 = 0.f;
    for (int f = 0; f < NFREQ; ++f) {
        float w = (f == 0 || f == 256) ? 1.0f : 2.0f;
        float c = w * ctab[(f * t) & 511];
        int s = rms[f];
        acc0 += (s == 0) ? c : 0.0f;
        acc1 += (s == 1) ? c : 0.0f;
        acc2 += (s == 2) ? c : 0.0f;
        acc3 += (s == 3) ? c : 0.0f;
    }
    const float sc = 1.0f / 512.0f;
    Kmat[0 * 512 + t] = acc0 * sc;
    Kmat[1 * 512 + t] = acc1 * sc;
    Kmat[2 * 512 + t] = acc2 * sc;
    Kmat[3 * 512 + t] = acc3 * sc;
}

// ---------------- W[n][s*128+d] = sum_p proj[p][d] * K_s[(p-n)&511] --------------------
__global__ __launch_bounds__(128) void build_W_kernel(const float* __restrict__ proj,
                                                      const float* __restrict__ Kmat,
                                                      float* __restrict__ W) {
    int n = blockIdx.x, s = blockIdx.y, d = threadIdx.x;
    __shared__ float Ks[512];
    for (int i = d; i < 512; i += 128) Ks[i] = Kmat[s * 512 + i];
    __syncthreads();
    float acc = 0.0f;
#pragma unroll 8
    for (int p = 0; p < 512; ++p)
        acc = fmaf(proj[p * DDIM + d], Ks[(p - n) & 511], acc);
    W[n * 512 + s * DDIM + d] = acc;
}

// ---------------- normalized codebook: cbn[m][:] = cb[m][:]/||cb[m]|| ------------------
__global__ __launch_bounds__(64) void cbnorm_kernel(const float* __restrict__ cb,
                                                    float* __restrict__ cbn) {
    int row = blockIdx.x;       // 8192
    int lane = threadIdx.x;     // 64
    float2 v = ((const float2*)(cb + row * DDIM))[lane];
    float ss = fmaf(v.x, v.x, v.y * v.y);
#pragma unroll
    for (int off = 32; off > 0; off >>= 1) ss += __shfl_down(ss, off);
    ss = __shfl(ss, 0);
    float r = 1.0f / sqrtf(ss);
    float2 o; o.x = v.x * r; o.y = v.y * r;
    ((float2*)(cbn + row * DDIM))[lane] = o;
}

// ---------------- feat[8192][512] = x[8192][512] @ W[512][512] -------------------------
__global__ __launch_bounds__(256) void feat_gemm(const float* __restrict__ A,
                                                 const float* __restrict__ Bw,
                                                 float* __restrict__ C) {
    __shared__ float As[64][36];   // 64 rows x 32 k (pad to 36: 144B stride, 16B aligned)
    __shared__ float Bs[32][68];   // 32 k x 64 cols (272B stride, 16B aligned)
    int t = threadIdx.x;
    int tx = t & 15, ty = t >> 4;
    int row0 = blockIdx.x * 64, col0 = blockIdx.y * 64;
    float acc[4][4] = {};
    for (int kt = 0; kt < 512; kt += 32) {
        __syncthreads();
        {
            int ar = t >> 3, ak = (t & 7) * 4;          // rows 0..31 (+32), 32 k per row
            float4 a0 = *(const float4*)(A + (row0 + ar) * NDIM + kt + ak);
            float4 a1 = *(const float4*)(A + (row0 + ar + 32) * NDIM + kt + ak);
            *(float4*)&As[ar][ak] = a0;
            *(float4*)&As[ar + 32][ak] = a1;
            int bk = t >> 4, bc = (t & 15) * 4;         // k 0..15 (+16), 64 cols
            float4 b0 = *(const float4*)(Bw + (kt + bk) * 512 + col0 + bc);
            float4 b1 = *(const float4*)(Bw + (kt + bk + 16) * 512 + col0 + bc);
            *(float4*)&Bs[bk][bc] = b0;
            *(float4*)&Bs[bk + 16][bc] = b1;
        }
        __syncthreads();
#pragma unroll
        for (int k = 0; k < 32; ++k) {
            float a[4];
#pragma unroll
            for (int i = 0; i < 4; ++i) a[i] = As[ty * 4 + i][k];
            float4 b = *(float4*)&Bs[k][tx * 4];
#pragma unroll
            for (int i = 0; i < 4; ++i) {
                acc[i][0] = fmaf(a[i], b.x, acc[i][0]);
                acc[i][1] = fmaf(a[i], b.y, acc[i][1]);
                acc[i][2] = fmaf(a[i], b.z, acc[i][2]);
                acc[i][3] = fmaf(a[i], b.w, acc[i][3]);
            }
        }
    }
#pragma unroll
    for (int i = 0; i < 4; ++i)
#pragma unroll
        for (int j = 0; j < 4; ++j)
            C[(row0 + ty * 4 + i) * 512 + col0 + tx * 4 + j] = acc[i][j];
}

// ---------------- sim + argmax: rows=[32768][128] vs cbn[8192][128] --------------------
__global__ __launch_bounds__(256) void sim_argmax(const float* __restrict__ feat,
                                                  const float* __restrict__ cbn,
                                                  int* __restrict__ out) {
    __shared__ float Af[64][132];     // 64 feat rows x 128 (528B stride, 16B aligned)
    __shared__ float Bs[64][36];      // 64 codes x 32 k
    __shared__ float redv[64][16];
    __shared__ int   redi[64][16];
    int t = threadIdx.x;
    int tx = t & 15, ty = t >> 4;
    int row0 = blockIdx.x * 64;
    // stage 64 feat rows
#pragma unroll
    for (int i = 0; i < 8; ++i) {
        int slot = t + i * 256;               // 0..2047 float4 slots
        int r = slot >> 5, c4 = (slot & 31) * 4;
        float4 v = *(const float4*)(feat + (row0 + r) * DDIM + c4);
        *(float4*)&Af[r][c4] = v;
    }
    float best[4] = {-1e30f, -1e30f, -1e30f, -1e30f};
    int bidx[4] = {0, 0, 0, 0};
    for (int c0 = 0; c0 < NEMBED; c0 += 64) {
        float acc[4][4] = {};
#pragma unroll
        for (int kt = 0; kt < 128; kt += 32) {
            int code = t >> 3, kq = (t & 7) * 4;
            float4 v0 = *(const float4*)(cbn + (c0 + code) * DDIM + kt + kq);
            float4 v1 = *(const float4*)(cbn + (c0 + code + 32) * DDIM + kt + kq);
            __syncthreads();   // prev compute done reading Bs (also covers Af on first pass)
            *(float4*)&Bs[code][kq] = v0;
            *(float4*)&Bs[code + 32][kq] = v1;
            __syncthreads();
#pragma unroll
            for (int k = 0; k < 32; k += 4) {
                float4 a[4], b[4];
#pragma unroll
                for (int i = 0; i < 4; ++i) a[i] = *(float4*)&Af[ty * 4 + i][kt + k];
#pragma unroll
                for (int j = 0; j < 4; ++j) b[j] = *(float4*)&Bs[tx * 4 + j][k];
#pragma unroll
                for (int i = 0; i < 4; ++i)
#pragma unroll
                    for (int j = 0; j < 4; ++j) {
                        acc[i][j] = fmaf(a[i].x, b[j].x, acc[i][j]);
                        acc[i][j] = fmaf(a[i].y, b[j].y, acc[i][j]);
                        acc[i][j] = fmaf(a[i].z, b[j].z, acc[i][j]);
                        acc[i][j] = fmaf(a[i].w, b[j].w, acc[i][j]);
                    }
            }
        }
        // update per-row running argmax (indices ascend => strict '>' keeps first max)
#pragma unroll
        for (int j = 0; j < 4; ++j) {
            int cidx = c0 + tx * 4 + j;
#pragma unroll
            for (int i = 0; i < 4; ++i) {
                float v = acc[i][j];
                if (v > best[i]) { best[i] = v; bidx[i] = cidx; }
            }
        }
    }
    __syncthreads();
#pragma unroll
    for (int i = 0; i < 4; ++i) { redv[ty * 4 + i][tx] = best[i]; redi[ty * 4 + i][tx] = bidx[i]; }
    __syncthreads();
    if (t < 64) {
        float bv = redv[t][0]; int bi = redi[t][0];
#pragma unroll
        for (int xx = 1; xx < 16; ++xx) {
            float v = redv[t][xx]; int ii = redi[t][xx];
            if (v > bv || (v == bv && ii < bi)) { bv = v; bi = ii; }
        }
        out[row0 + t] = bi;
    }
}

extern "C" void kernel_launch(void* const* d_in, const int* in_sizes, int n_in,
                              void* d_out, int out_size, void* d_ws, size_t ws_size,
                              hipStream_t stream) {
    const float* x    = (const float*)d_in[0];   // [32,256,512]
    const float* proj = (const float*)d_in[1];   // [512,128]
    const float* cb   = (const float*)d_in[2];   // [1,8192,128]
    const int*   rm   = (const int*)d_in[3];     // [257]
    int* out = (int*)d_out;                      // [32,256,4,1] int32

    float* ws   = (float*)d_ws;
    float* Kmat = ws;                  // 4*512            = 2048 floats
    float* W    = Kmat + 2048;         // 512*512          = 262144
    float* cbn  = W + 262144;          // 8192*128         = 1048576
    float* feat = cbn + 1048576;       // 8192*512         = 4194304
    // total ~22 MB of ws

    build_K_kernel<<<1, 512, 0, stream>>>(rm, Kmat);
    cbnorm_kernel<<<NEMBED, 64, 0, stream>>>(cb, cbn);
    build_W_kernel<<<dim3(512, 4), 128, 0, stream>>>(proj, Kmat, W);
    feat_gemm<<<dim3(BT / 64, 8), 256, 0, stream>>>(x, W, feat);
    sim_argmax<<<32768 / 64, 256, 0, stream>>>(feat, cbn, out);
}

// Round 2
// 415.809 us; speedup vs baseline: 4.5364x; 4.5364x over previous
//
#include <hip/hip_runtime.h>
#include <math.h>

#define BT 8192      // B*T
#define NDIM 512     // INPUT_DIM
#define NFREQ 257
#define DDIM 128     // VQ_DIM
#define NEMBED 8192

typedef _Float16 half8 __attribute__((ext_vector_type(8)));
typedef _Float16 half2v __attribute__((ext_vector_type(2)));
typedef float f32x4 __attribute__((ext_vector_type(4)));

#define SCALE_DN 2.44140625e-4f   // 2^-12

// ---------------- K table: K_s[delta] = sum_{f: rm[f]==s} w_f cos(2*pi*f*delta/512) ----
__global__ __launch_bounds__(512) void build_K_kernel(const int* __restrict__ rm,
                                                      float* __restrict__ Kmat) {
    __shared__ float ctab[512];
    __shared__ int rms[NFREQ];
    int t = threadIdx.x;
    ctab[t] = cospif((float)t * (1.0f / 256.0f));   // cos(2*pi*t/512)
    if (t < NFREQ) rms[t] = rm[t];
    __syncthreads();
    float acc0 = 0.f, acc1 = 0.f, acc2 = 0.f, acc3 = 0.f;
    for (int f = 0; f < NFREQ; ++f) {
        float w = (f == 0 || f == 256) ? 1.0f : 2.0f;
        float c = w * ctab[(f * t) & 511];
        int s = rms[f];
        acc0 += (s == 0) ? c : 0.0f;
        acc1 += (s == 1) ? c : 0.0f;
        acc2 += (s == 2) ? c : 0.0f;
        acc3 += (s == 3) ? c : 0.0f;
    }
    const float sc = 1.0f / 512.0f;
    Kmat[0 * 512 + t] = acc0 * sc;
    Kmat[1 * 512 + t] = acc1 * sc;
    Kmat[2 * 512 + t] = acc2 * sc;
    Kmat[3 * 512 + t] = acc3 * sc;
}

// ---------------- W[n][s*128+d] = sum_p proj[p][d] * K_s[(p-n)&511] --------------------
__global__ __launch_bounds__(128) void build_W_kernel(const float* __restrict__ proj,
                                                      const float* __restrict__ Kmat,
                                                      float* __restrict__ W) {
    int n = blockIdx.x, s = blockIdx.y, d = threadIdx.x;
    __shared__ float Ks[512];
    for (int i = d; i < 512; i += 128) Ks[i] = Kmat[s * 512 + i];
    __syncthreads();
    float acc = 0.0f;
#pragma unroll 8
    for (int p = 0; p < 512; ++p)
        acc = fmaf(proj[p * DDIM + d], Ks[(p - n) & 511], acc);
    W[n * 512 + s * DDIM + d] = acc;
}

// ---------------- feat[8192][512] = x[8192][512] @ W[512][512] -------------------------
__global__ __launch_bounds__(256) void feat_gemm(const float* __restrict__ A,
                                                 const float* __restrict__ Bw,
                                                 float* __restrict__ C) {
    __shared__ float As[64][36];
    __shared__ float Bs[32][68];
    int t = threadIdx.x;
    int tx = t & 15, ty = t >> 4;
    int row0 = blockIdx.x * 64, col0 = blockIdx.y * 64;
    float acc[4][4] = {};
    for (int kt = 0; kt < 512; kt += 32) {
        __syncthreads();
        {
            int ar = t >> 3, ak = (t & 7) * 4;
            float4 a0 = *(const float4*)(A + (row0 + ar) * NDIM + kt + ak);
            float4 a1 = *(const float4*)(A + (row0 + ar + 32) * NDIM + kt + ak);
            *(float4*)&As[ar][ak] = a0;
            *(float4*)&As[ar + 32][ak] = a1;
            int bk = t >> 4, bc = (t & 15) * 4;
            float4 b0 = *(const float4*)(Bw + (kt + bk) * 512 + col0 + bc);
            float4 b1 = *(const float4*)(Bw + (kt + bk + 16) * 512 + col0 + bc);
            *(float4*)&Bs[bk][bc] = b0;
            *(float4*)&Bs[bk + 16][bc] = b1;
        }
        __syncthreads();
#pragma unroll
        for (int k = 0; k < 32; ++k) {
            float a[4];
#pragma unroll
            for (int i = 0; i < 4; ++i) a[i] = As[ty * 4 + i][k];
            float4 b = *(float4*)&Bs[k][tx * 4];
#pragma unroll
            for (int i = 0; i < 4; ++i) {
                acc[i][0] = fmaf(a[i], b.x, acc[i][0]);
                acc[i][1] = fmaf(a[i], b.y, acc[i][1]);
                acc[i][2] = fmaf(a[i], b.z, acc[i][2]);
                acc[i][3] = fmaf(a[i], b.w, acc[i][3]);
            }
        }
    }
#pragma unroll
    for (int i = 0; i < 4; ++i)
#pragma unroll
        for (int j = 0; j < 4; ++j)
            C[(row0 + ty * 4 + i) * 512 + col0 + tx * 4 + j] = acc[i][j];
}

// ---------------- normalize rows of [rows][128] f32 and split into f16 hi/lo -----------
// hi = f16(v), lo = f16((v-hi)*4096). Per-row positive scaling preserves argmax.
__global__ __launch_bounds__(256) void norm_split(const float* __restrict__ src,
                                                  _Float16* __restrict__ hi,
                                                  _Float16* __restrict__ lo) {
    int row = blockIdx.x * 4 + (threadIdx.x >> 6);
    int lane = threadIdx.x & 63;
    float2 v = ((const float2*)(src + (size_t)row * DDIM))[lane];
    float ss = fmaf(v.x, v.x, v.y * v.y);
#pragma unroll
    for (int off = 32; off; off >>= 1) ss += __shfl_xor(ss, off);
    float r = 1.0f / sqrtf(ss);
    float a = v.x * r, b = v.y * r;
    _Float16 ha = (_Float16)a, hb = (_Float16)b;
    _Float16 la = (_Float16)((a - (float)ha) * 4096.0f);
    _Float16 lb = (_Float16)((b - (float)hb) * 4096.0f);
    half2v hv = {ha, hb}, lv = {la, lb};
    *(half2v*)(hi + (size_t)row * DDIM + 2 * lane) = hv;
    *(half2v*)(lo + (size_t)row * DDIM + 2 * lane) = lv;
}

// ---------------- MFMA sim + argmax: feat[32768][128] x cb[8192][128]^T ----------------
// Per block: 64 feat rows (4 waves x one 16-row M-tile), scan all 8192 codes.
// sim = hihi + 2^-12 * (hi*lo + lo*hi); 3 independent acc chains per wave.
__global__ __launch_bounds__(256) void sim_argmax_mfma(const _Float16* __restrict__ fhi,
                                                       const _Float16* __restrict__ flo,
                                                       const _Float16* __restrict__ chi,
                                                       const _Float16* __restrict__ clo,
                                                       int* __restrict__ out) {
    __shared__ _Float16 Bhi[2][16 * 128];   // 16 codes x 128 k, XOR-swizzled chunks
    __shared__ _Float16 Blo[2][16 * 128];
    __shared__ float redv[64][16];
    __shared__ int   redi[64][16];

    int t = threadIdx.x;
    int w = t >> 6;                // wave id 0..3
    int lr = t & 15;               // fragment row/col index (lane&15)
    int lg = (t >> 4) & 3;         // k-group (lane>>4)
    int row0 = blockIdx.x * 64;

    // A fragments in registers for the whole scan: row = row0 + w*16 + lr, k = kt*32+lg*8
    half8 ahi[4], alo[4];
    {
        const _Float16* pa = fhi + (size_t)(row0 + w * 16 + lr) * DDIM + lg * 8;
        const _Float16* pb = flo + (size_t)(row0 + w * 16 + lr) * DDIM + lg * 8;
#pragma unroll
        for (int kt = 0; kt < 4; ++kt) {
            ahi[kt] = *(const half8*)(pa + kt * 32);
            alo[kt] = *(const half8*)(pb + kt * 32);
        }
    }

    // LDS read offsets (f16 elems): row lr, 16B-chunk (4kt+lg) ^ (lr&7)
    int roff[4];
#pragma unroll
    for (int kt = 0; kt < 4; ++kt)
        roff[kt] = lr * 128 + (((kt << 2) | lg) ^ (lr & 7)) * 8;

    // staging map: thread t -> tile row t>>4, chunk t&15 ; dst chunk XOR-swizzled
    int srow = t >> 4, sc = t & 15;
    int sdst = srow * 128 + ((sc ^ (srow & 7)) * 8);
    const _Float16* shsrc = chi + (size_t)srow * DDIM + sc * 8;
    const _Float16* slsrc = clo + (size_t)srow * DDIM + sc * 8;

    float best[4] = {-1e30f, -1e30f, -1e30f, -1e30f};
    int   bidx[4] = {0, 0, 0, 0};

    // prologue: stage tile 0 into buf 0
    {
        half8 h = *(const half8*)shsrc;
        half8 q = *(const half8*)slsrc;
        *(half8*)&Bhi[0][sdst] = h;
        *(half8*)&Blo[0][sdst] = q;
    }

    const int NT = NEMBED / 16;   // 512
    for (int it = 0; it < NT; ++it) {
        __syncthreads();
        int buf = it & 1;
        half8 nh, nl;
        bool have = (it + 1 < NT);
        if (have) {   // issue next-tile loads early (latency hides under MFMA)
            nh = *(const half8*)(shsrc + (size_t)(it + 1) * 16 * DDIM);
            nl = *(const half8*)(slsrc + (size_t)(it + 1) * 16 * DDIM);
        }
        f32x4 a0 = {0.f, 0.f, 0.f, 0.f}, a1 = a0, a2 = a0;
#pragma unroll
        for (int kt = 0; kt < 4; ++kt) {
            half8 bh = *(half8*)&Bhi[buf][roff[kt]];
            half8 bl = *(half8*)&Blo[buf][roff[kt]];
            a0 = __builtin_amdgcn_mfma_f32_16x16x32_f16(ahi[kt], bh, a0, 0, 0, 0);
            a1 = __builtin_amdgcn_mfma_f32_16x16x32_f16(ahi[kt], bl, a1, 0, 0, 0);
            a2 = __builtin_amdgcn_mfma_f32_16x16x32_f16(alo[kt], bh, a2, 0, 0, 0);
        }
        int n0 = it * 16;
#pragma unroll
        for (int r = 0; r < 4; ++r) {
            float s = fmaf(a1[r] + a2[r], SCALE_DN, a0[r]);
            if (s > best[r]) { best[r] = s; bidx[r] = n0 + lr; }
        }
        if (have) {   // write-late into the other buffer
            *(half8*)&Bhi[buf ^ 1][sdst] = nh;
            *(half8*)&Blo[buf ^ 1][sdst] = nl;
        }
    }

    // D layout: lane holds rows m=4*lg+r, col lr of its wave's tile
#pragma unroll
    for (int r = 0; r < 4; ++r) {
        redv[w * 16 + 4 * lg + r][lr] = best[r];
        redi[w * 16 + 4 * lg + r][lr] = bidx[r];
    }
    __syncthreads();
    if (t < 64) {
        float bv = redv[t][0]; int bi = redi[t][0];
#pragma unroll
        for (int c = 1; c < 16; ++c) {
            float v = redv[t][c]; int ii = redi[t][c];
            if (v > bv || (v == bv && ii < bi)) { bv = v; bi = ii; }
        }
        out[row0 + t] = bi;
    }
}

extern "C" void kernel_launch(void* const* d_in, const int* in_sizes, int n_in,
                              void* d_out, int out_size, void* d_ws, size_t ws_size,
                              hipStream_t stream) {
    const float* x    = (const float*)d_in[0];   // [32,256,512]
    const float* proj = (const float*)d_in[1];   // [512,128]
    const float* cb   = (const float*)d_in[2];   // [1,8192,128]
    const int*   rm   = (const int*)d_in[3];     // [257]
    int* out = (int*)d_out;                      // [32,256,4,1] int32

    char* wsb = (char*)d_ws;
    float*     Kmat = (float*)(wsb);                        // 8 KB
    float*     W    = (float*)(wsb + 16384);                // 1 MB
    float*     feat = (float*)(wsb + 16384 + 1048576);      // 16 MB
    _Float16*  fhi  = (_Float16*)(wsb + 17842176);          // 8 MB
    _Float16*  flo  = (_Float16*)(wsb + 26230784);          // 8 MB
    _Float16*  chi  = (_Float16*)(wsb + 34619392);          // 2 MB
    _Float16*  clo  = (_Float16*)(wsb + 36716544);          // 2 MB (end ~37 MB)

    build_K_kernel<<<1, 512, 0, stream>>>(rm, Kmat);
    build_W_kernel<<<dim3(512, 4), 128, 0, stream>>>(proj, Kmat, W);
    feat_gemm<<<dim3(BT / 64, 8), 256, 0, stream>>>(x, W, feat);
    norm_split<<<32768 / 4, 256, 0, stream>>>(feat, fhi, flo);      // feat rows
    norm_split<<<NEMBED / 4, 256, 0, stream>>>(cb, chi, clo);       // codebook rows
    sim_argmax_mfma<<<32768 / 64, 256, 0, stream>>>(fhi, flo, chi, clo, out);
}